// Round 1
// baseline (2472.487 us; speedup 1.0000x reference)
//
#include <hip/hip_runtime.h>
#include <math.h>

#define NPTS  10000
#define KNB   32
#define NCELL 216     // 6*6*6
#define PB    16      // points per block (4 waves x 4 points)

// ---------------------------------------------------------------------------
// helpers
// ---------------------------------------------------------------------------
__device__ __forceinline__ float sgnf(float v) {
    return (v > 0.0f) ? 1.0f : ((v < 0.0f) ? -1.0f : 0.0f);
}

// Open3D ball->cube volume-preserving map, transcribed from the reference.
__device__ __forceinline__ void ball_to_cube(float x, float y, float z,
                                             float& X, float& Y, float& Z) {
    const float EPSF = 1e-12f;
    const float FOPI = (float)(4.0 / 3.14159265358979323846);
    float sq   = x * x + y * y + z * z;
    float norm = sqrtf(fmaxf(sq, EPSF));
    float rho2 = x * x + y * y;
    bool in_cone = (1.25f * z * z > rho2);
    float s1 = sqrtf(3.0f * norm / (norm + fabsf(z)));
    float s2 = norm / sqrtf(fmaxf(rho2, EPSF));
    float s  = in_cone ? s1 : s2;
    float xc = x * s;
    float yc = y * s;
    float zc = in_cone ? sgnf(z) * norm : 1.5f * z;
    if (sq < EPSF) { xc = 0.0f; yc = 0.0f; zc = 0.0f; }
    float sq_xy   = xc * xc + yc * yc;
    float norm_xy = sqrtf(fmaxf(sq_xy, EPSF));
    bool x_major = (fabsf(yc) <= fabsf(xc));
    float xd = (fabsf(xc) < EPSF) ? 1.0f : xc;
    float yd = (fabsf(yc) < EPSF) ? 1.0f : yc;
    float tx = sgnf(xc) * norm_xy;
    float ty = sgnf(yc) * norm_xy;
    float xq = x_major ? tx : ty * FOPI * atanf(xc / yd);
    float yq = x_major ? tx * FOPI * atanf(yc / xd) : ty;
    if (sq_xy < EPSF) { xq = 0.0f; yq = 0.0f; }
    X = xq; Y = yq; Z = zc;
}

// ---------------------------------------------------------------------------
// Kernel 1: per-(point,neighbor) geometry record + neighbor counts.
// Record (uint4): x,y,z = trilinear fracs (fp32 bits); w = packed:
//   [7:0]=c000 cell, [8]=dx?, [9]=dy?, [10]=dz?, [11]=valid, [25:12]=nidx
// Mask is recomputed exactly (fp32, no contraction) as d2 <= 2.25.
// nidx==0 padding: only the FIRST zero slot of a row may be genuine.
// ---------------------------------------------------------------------------
__global__ __launch_bounds__(256) void geom_kernel(
    const float* __restrict__ pos, const int* __restrict__ nidx,
    uint4* __restrict__ geo, float* __restrict__ cnt) {
    int t = blockIdx.x * 256 + threadIdx.x;
    if (t >= NPTS * KNB) return;
    int j = t >> 5;
    int k = t & 31;
    int nid = nidx[t];
    float px = pos[j * 3], py = pos[j * 3 + 1], pz = pos[j * 3 + 2];
    float qx = pos[nid * 3], qy = pos[nid * 3 + 1], qz = pos[nid * 3 + 2];
    // exact fp32 (no FMA contraction) to reproduce numpy's mask bit-for-bit
    float dx = __fsub_rn(px, qx), dy = __fsub_rn(py, qy), dz = __fsub_rn(pz, qz);
    float d2 = __fadd_rn(__fadd_rn(__fmul_rn(dx, dx), __fmul_rn(dy, dy)),
                         __fmul_rn(dz, dz));
    bool valid = (d2 <= 2.25f);
    if (valid && nid == 0) {
        // genuine zero-neighbor only allowed once per row (first slot wins)
        for (int kk = 0; kk < k; ++kk) {
            if (nidx[j * KNB + kk] == 0) { valid = false; break; }
        }
    }
    uint4 g = make_uint4(0u, 0u, 0u, 0u);
    if (valid) {
        const float C = (float)(2.0 / 3.0);   // 2/EXTENT
        float ux = (qx - px) * C, uy = (qy - py) * C, uz = (qz - pz) * C;
        float X, Y, Z;
        ball_to_cube(ux, uy, uz, X, Y, Z);
        float cs[3] = { (X + 1.0f) * 2.5f, (Y + 1.0f) * 2.5f, (Z + 1.0f) * 2.5f };
        int i0[3], i1[3];
        float fr[3];
        #pragma unroll
        for (int d = 0; d < 3; ++d) {
            float f0 = floorf(cs[d]);
            fr[d] = cs[d] - f0;                   // frac from UNCLIPPED floor (ref semantics)
            int a = (int)f0;
            a = min(max(a, 0), 5);
            i0[d] = a;
            i1[d] = min(a + 1, 5);
        }
        int c000 = (i0[0] * 6 + i0[1]) * 6 + i0[2];
        unsigned bits = (unsigned)c000
                      | ((unsigned)(i1[0] - i0[0]) << 8)
                      | ((unsigned)(i1[1] - i0[1]) << 9)
                      | ((unsigned)(i1[2] - i0[2]) << 10)
                      | (1u << 11)
                      | ((unsigned)nid << 12);
        g.x = __float_as_uint(fr[0]);
        g.y = __float_as_uint(fr[1]);
        g.z = __float_as_uint(fr[2]);
        g.w = bits;
        atomicAdd(&cnt[j], 1.0f);
    }
    geo[t] = g;
}

// ---------------------------------------------------------------------------
// Kernel 2: continuous conv. One block = 16 points (4 waves x 4 point-slots).
// Phase 1: counting-sort the <=4096 corner contributions by (wave, cell).
// Phase 2: loop cells; each lane caches W[m][:, co] in CIN VGPRs; stream the
//          cell's contributions (wave-uniform -> scalar feature loads).
// ---------------------------------------------------------------------------
template<int CIN, int COUT>
__global__ __launch_bounds__(256) void conv_kernel(
    const float* __restrict__ feats, const float* __restrict__ W,
    const float* __restrict__ bias, const uint4* __restrict__ geo,
    const float* __restrict__ cnt, float* __restrict__ out) {
    static_assert(CIN % 4 == 0, "CIN multiple of 4");
    __shared__ uint2 contribs[4096];      // 32 KB: per-wave fixed regions of 1024
    __shared__ int   bstart[4 * NCELL];   // bucket starts, key = wave*216 + cell
    __shared__ int   bcur[4 * NCELL];     // histogram / cursor / bucket ends

    const int tid  = threadIdx.x;
    const int wv   = tid >> 6;
    const int lane = tid & 63;
    const int base = blockIdx.x * PB;

    for (int i = tid; i < 4 * NCELL; i += 256) bcur[i] = 0;
    __syncthreads();

    // ---- pass 1: histogram ------------------------------------------------
    for (int pr = tid; pr < PB * KNB; pr += 256) {
        int pl = pr >> 5, k = pr & 31;
        uint4 g = geo[(base + pl) * KNB + k];
        if (g.w & 2048u) {
            int c000 = g.w & 255u;
            int dxo = (g.w & 256u)  ? 36 : 0;
            int dyo = (g.w & 512u)  ? 6  : 0;
            int dzo = (g.w & 1024u) ? 1  : 0;
            int ow  = pl >> 2;
            #pragma unroll
            for (int c = 0; c < 8; ++c) {
                int cell = c000 + ((c & 4) ? dxo : 0) + ((c & 2) ? dyo : 0)
                                + ((c & 1) ? dzo : 0);
                atomicAdd(&bcur[ow * NCELL + cell], 1);
            }
        }
    }
    __syncthreads();
    // ---- exclusive scan: 4 independent 216-bucket scans (one per wave) ----
    if (tid < 4) {
        int run = tid * 1024;
        for (int m = 0; m < NCELL; ++m) {
            int c = bcur[tid * NCELL + m];
            bstart[tid * NCELL + m] = run;
            run += c;
        }
    }
    __syncthreads();
    for (int i = tid; i < 4 * NCELL; i += 256) bcur[i] = bstart[i];
    __syncthreads();
    // ---- pass 2: scatter --------------------------------------------------
    for (int pr = tid; pr < PB * KNB; pr += 256) {
        int pl = pr >> 5, k = pr & 31;
        uint4 g = geo[(base + pl) * KNB + k];
        if (g.w & 2048u) {
            float fx = __uint_as_float(g.x);
            float fy = __uint_as_float(g.y);
            float fz = __uint_as_float(g.z);
            int c000 = g.w & 255u;
            int dxo = (g.w & 256u)  ? 36 : 0;
            int dyo = (g.w & 512u)  ? 6  : 0;
            int dzo = (g.w & 1024u) ? 1  : 0;
            int nid = (g.w >> 12) & 16383u;
            int ow = pl >> 2, slot = pl & 3;
            unsigned payload = ((unsigned)slot << 14) | (unsigned)nid;
            #pragma unroll
            for (int c = 0; c < 8; ++c) {
                float wgt = ((c & 4) ? fx : 1.0f - fx)
                          * ((c & 2) ? fy : 1.0f - fy)
                          * ((c & 1) ? fz : 1.0f - fz);
                int cell = c000 + ((c & 4) ? dxo : 0) + ((c & 2) ? dyo : 0)
                                + ((c & 1) ? dzo : 0);
                int idx = atomicAdd(&bcur[ow * NCELL + cell], 1);
                contribs[idx] = make_uint2(__float_as_uint(wgt), payload);
            }
        }
    }
    __syncthreads();

    // ---- main loop over cells --------------------------------------------
    const int co = lane % COUT;   // COUT<64: upper lanes duplicate (store-masked)
    float a0 = 0.0f, a1 = 0.0f, a2 = 0.0f, a3 = 0.0f;
    for (int m = 0; m < NCELL; ++m) {
        float wreg[CIN];
        const float* wb = W + (size_t)(m * CIN) * COUT + co;
        #pragma unroll
        for (int ci = 0; ci < CIN; ++ci) wreg[ci] = wb[ci * COUT];
        int s = bstart[wv * NCELL + m];
        int e = bcur[wv * NCELL + m];
        for (int idx = s; idx < e; ++idx) {
            uint2 cc = contribs[idx];               // broadcast LDS read
            float wgt = __uint_as_float(cc.x);
            int payload = __builtin_amdgcn_readfirstlane((int)cc.y);
            int nid  = payload & 16383;
            int slot = payload >> 14;               // wave-uniform
            const float* f = feats + (size_t)nid * CIN;
            float t0 = 0.0f, t1 = 0.0f, t2 = 0.0f, t3 = 0.0f;
            #pragma unroll
            for (int ci = 0; ci < CIN; ci += 4) {
                t0 = fmaf(f[ci],     wreg[ci],     t0);
                t1 = fmaf(f[ci + 1], wreg[ci + 1], t1);
                t2 = fmaf(f[ci + 2], wreg[ci + 2], t2);
                t3 = fmaf(f[ci + 3], wreg[ci + 3], t3);
            }
            float t = ((t0 + t1) + (t2 + t3)) * wgt;
            if      (slot == 0) a0 += t;
            else if (slot == 1) a1 += t;
            else if (slot == 2) a2 += t;
            else                a3 += t;
        }
        __syncthreads();   // keep waves cell-aligned so W[m] hits L1
    }

    // ---- epilogue: normalize, bias, relu ---------------------------------
    if (lane < COUT) {
        float b = bias[co];
        #pragma unroll
        for (int s2 = 0; s2 < 4; ++s2) {
            int n = base + wv * 4 + s2;
            float a = (s2 == 0) ? a0 : (s2 == 1) ? a1 : (s2 == 2) ? a2 : a3;
            float c = cnt[n];
            if (c > 0.0f) a /= fmaxf(c, 1.0f);
            a = fmaxf(a + b, 0.0f);
            out[(size_t)n * COUT + co] = a;
        }
    }
}

// ---------------------------------------------------------------------------
// Kernel 3: fused FC chain. One wave per point, __shfl broadcasts activations.
// ---------------------------------------------------------------------------
__global__ __launch_bounds__(64) void fc_kernel(
    const float* __restrict__ x,
    const float* __restrict__ W1, const float* __restrict__ b1,
    const float* __restrict__ W2, const float* __restrict__ b2,
    const float* __restrict__ W3, const float* __restrict__ b3,
    const float* __restrict__ W4, const float* __restrict__ b4,
    float* __restrict__ out) {
    int n = blockIdx.x;
    int lane = threadIdx.x;
    float xv = (lane < 32) ? x[(size_t)n * 32 + lane] : 0.0f;

    float t = b1[lane];
    for (int ci = 0; ci < 32; ++ci)
        t = fmaf(__shfl(xv, ci), W1[ci * 64 + lane], t);
    float h1 = fmaxf(t, 0.0f);

    t = b2[lane];
    for (int ci = 0; ci < 64; ++ci)
        t = fmaf(__shfl(h1, ci), W2[ci * 64 + lane], t);
    float h2 = fmaxf(t, 0.0f);

    int l32 = lane & 31;
    t = b3[l32];
    for (int ci = 0; ci < 64; ++ci)
        t = fmaf(__shfl(h2, ci), W3[ci * 32 + l32], t);
    float h3 = fmaxf(t, 0.0f);        // lanes 0..31 hold h3; 32..63 duplicates

    int ch = (lane < 3) ? lane : 0;   // avoid divergent shuffles
    float o = b4[ch];
    for (int ci = 0; ci < 32; ++ci)
        o = fmaf(__shfl(h3, ci), W4[ci * 3 + ch], o);
    if (lane < 3) out[(size_t)n * 3 + lane] = o;
}

// ---------------------------------------------------------------------------
// launch
// ---------------------------------------------------------------------------
extern "C" void kernel_launch(void* const* d_in, const int* in_sizes, int n_in,
                              void* d_out, int out_size, void* d_ws, size_t ws_size,
                              hipStream_t stream) {
    const float* feats = (const float*)d_in[0];
    const float* pos   = (const float*)d_in[1];
    const int*   nidx  = (const int*)d_in[2];
    // d_in[3] (neighbor_mask) intentionally unused: mask recomputed exactly.
    const float* W1 = (const float*)d_in[4];
    const float* b1 = (const float*)d_in[5];
    const float* W2 = (const float*)d_in[6];
    const float* b2 = (const float*)d_in[7];
    const float* W3 = (const float*)d_in[8];
    const float* b3 = (const float*)d_in[9];
    const float* Wfc1 = (const float*)d_in[10];
    const float* bfc1 = (const float*)d_in[11];
    const float* Wfc2 = (const float*)d_in[12];
    const float* bfc2 = (const float*)d_in[13];
    const float* Wfc3 = (const float*)d_in[14];
    const float* bfc3 = (const float*)d_in[15];
    const float* Wout = (const float*)d_in[16];
    const float* bout = (const float*)d_in[17];

    char* ws = (char*)d_ws;
    uint4* geo = (uint4*)(ws);                       // 10000*32*16 = 5,120,000 B
    float* cnt = (float*)(ws + 5120000);             //    40,000 B
    float* x1  = (float*)(ws + 5160000);             // 2,560,000 B  [N][64]
    float* x2  = (float*)(ws + 7720000);             // 2,560,000 B  [N][64]
    float* x3  = (float*)(ws + 10280000);            // 1,280,000 B  [N][32]

    hipMemsetAsync(cnt, 0, NPTS * sizeof(float), stream);
    geom_kernel<<<(NPTS * KNB) / 256, 256, 0, stream>>>(pos, nidx, geo, cnt);

    conv_kernel<4, 64><<<NPTS / PB, 256, 0, stream>>>(feats, W1, b1, geo, cnt, x1);
    conv_kernel<64, 64><<<NPTS / PB, 256, 0, stream>>>(x1, W2, b2, geo, cnt, x2);
    conv_kernel<64, 32><<<NPTS / PB, 256, 0, stream>>>(x2, W3, b3, geo, cnt, x3);

    fc_kernel<<<NPTS, 64, 0, stream>>>(x3, Wfc1, bfc1, Wfc2, bfc2,
                                       Wfc3, bfc3, Wout, bout, (float*)d_out);
}

// Round 2
// 2287.706 us; speedup vs baseline: 1.0808x; 1.0808x over previous
//
#include <hip/hip_runtime.h>
#include <math.h>

#define NPTS  10000
#define KNB   32
#define NCELL 216     // 6*6*6
#define NSGT  157     // ceil(NPTS/64) sort groups

// ---------------------------------------------------------------------------
// helpers
// ---------------------------------------------------------------------------
__device__ __forceinline__ float sgnf(float v) {
    return (v > 0.0f) ? 1.0f : ((v < 0.0f) ? -1.0f : 0.0f);
}

// Open3D ball->cube volume-preserving map, transcribed from the reference.
__device__ __forceinline__ void ball_to_cube(float x, float y, float z,
                                             float& X, float& Y, float& Z) {
    const float EPSF = 1e-12f;
    const float FOPI = (float)(4.0 / 3.14159265358979323846);
    float sq   = x * x + y * y + z * z;
    float norm = sqrtf(fmaxf(sq, EPSF));
    float rho2 = x * x + y * y;
    bool in_cone = (1.25f * z * z > rho2);
    float s1 = sqrtf(3.0f * norm / (norm + fabsf(z)));
    float s2 = norm / sqrtf(fmaxf(rho2, EPSF));
    float s  = in_cone ? s1 : s2;
    float xc = x * s;
    float yc = y * s;
    float zc = in_cone ? sgnf(z) * norm : 1.5f * z;
    if (sq < EPSF) { xc = 0.0f; yc = 0.0f; zc = 0.0f; }
    float sq_xy   = xc * xc + yc * yc;
    float norm_xy = sqrtf(fmaxf(sq_xy, EPSF));
    bool x_major = (fabsf(yc) <= fabsf(xc));
    float xd = (fabsf(xc) < EPSF) ? 1.0f : xc;
    float yd = (fabsf(yc) < EPSF) ? 1.0f : yc;
    float tx = sgnf(xc) * norm_xy;
    float ty = sgnf(yc) * norm_xy;
    float xq = x_major ? tx : ty * FOPI * atanf(xc / yd);
    float yq = x_major ? tx * FOPI * atanf(yc / xd) : ty;
    if (sq_xy < EPSF) { xq = 0.0f; yq = 0.0f; }
    X = xq; Y = yq; Z = zc;
}

// ---------------------------------------------------------------------------
// Kernel 1: per-(point,neighbor) geometry record + neighbor counts.
// Record (uint4): x,y,z = trilinear fracs (fp32 bits); w = packed:
//   [7:0]=c000 cell, [8]=dx?, [9]=dy?, [10]=dz?, [11]=valid, [25:12]=nidx
// ---------------------------------------------------------------------------
__global__ __launch_bounds__(256) void geom_kernel(
    const float* __restrict__ pos, const int* __restrict__ nidx,
    uint4* __restrict__ geo, float* __restrict__ cnt) {
    int t = blockIdx.x * 256 + threadIdx.x;
    if (t >= NPTS * KNB) return;
    int j = t >> 5;
    int k = t & 31;
    int nid = nidx[t];
    float px = pos[j * 3], py = pos[j * 3 + 1], pz = pos[j * 3 + 2];
    float qx = pos[nid * 3], qy = pos[nid * 3 + 1], qz = pos[nid * 3 + 2];
    // exact fp32 (no FMA contraction) to reproduce numpy's mask bit-for-bit
    float dx = __fsub_rn(px, qx), dy = __fsub_rn(py, qy), dz = __fsub_rn(pz, qz);
    float d2 = __fadd_rn(__fadd_rn(__fmul_rn(dx, dx), __fmul_rn(dy, dy)),
                         __fmul_rn(dz, dz));
    bool valid = (d2 <= 2.25f);
    if (valid && nid == 0) {
        for (int kk = 0; kk < k; ++kk) {
            if (nidx[j * KNB + kk] == 0) { valid = false; break; }
        }
    }
    uint4 g = make_uint4(0u, 0u, 0u, 0u);
    if (valid) {
        const float C = (float)(2.0 / 3.0);   // 2/EXTENT
        float ux = (qx - px) * C, uy = (qy - py) * C, uz = (qz - pz) * C;
        float X, Y, Z;
        ball_to_cube(ux, uy, uz, X, Y, Z);
        float cs[3] = { (X + 1.0f) * 2.5f, (Y + 1.0f) * 2.5f, (Z + 1.0f) * 2.5f };
        int i0[3], i1[3];
        float fr[3];
        #pragma unroll
        for (int d = 0; d < 3; ++d) {
            float f0 = floorf(cs[d]);
            fr[d] = cs[d] - f0;
            int a = (int)f0;
            a = min(max(a, 0), 5);
            i0[d] = a;
            i1[d] = min(a + 1, 5);
        }
        int c000 = (i0[0] * 6 + i0[1]) * 6 + i0[2];
        unsigned bits = (unsigned)c000
                      | ((unsigned)(i1[0] - i0[0]) << 8)
                      | ((unsigned)(i1[1] - i0[1]) << 9)
                      | ((unsigned)(i1[2] - i0[2]) << 10)
                      | (1u << 11)
                      | ((unsigned)nid << 12);
        g.x = __float_as_uint(fr[0]);
        g.y = __float_as_uint(fr[1]);
        g.z = __float_as_uint(fr[2]);
        g.w = bits;
        atomicAdd(&cnt[j], 1.0f);
    }
    geo[t] = g;
}

// ---------------------------------------------------------------------------
// Kernel 2: counting sort of corner contributions by (cell, pt) per 64-pt
// sort group. Output: contribs[sg][<=16384] (uint2: w, nid|ptl<<14) sorted by
// (cell, pt); coarse starts[sg][865] at (cell, 16-pt-wavegroup) granularity.
// Layer-independent: built once, consumed by all 3 conv layers.
// ---------------------------------------------------------------------------
__global__ __launch_bounds__(256) void sort_kernel(
    const uint4* __restrict__ geo, uint2* __restrict__ contribs,
    int* __restrict__ starts) {
    __shared__ int hist[13824];   // 216 cells * 64 pts
    __shared__ int part[257];
    const int sg = blockIdx.x, tid = threadIdx.x;
    for (int i = tid; i < 13824; i += 256) hist[i] = 0;
    __syncthreads();
    const int npts = min(64, NPTS - sg * 64);
    const int nrec = npts * KNB;
    const uint4* gb = geo + (size_t)sg * 64 * KNB;
    for (int r = tid; r < nrec; r += 256) {
        uint4 g = gb[r];
        if (g.w & 2048u) {
            int ptl = r >> 5;
            int c000 = g.w & 255u;
            int dxo = (g.w & 256u)  ? 36 : 0;
            int dyo = (g.w & 512u)  ? 6  : 0;
            int dzo = (g.w & 1024u) ? 1  : 0;
            #pragma unroll
            for (int c = 0; c < 8; ++c) {
                int cell = c000 + ((c & 4) ? dxo : 0) + ((c & 2) ? dyo : 0)
                                + ((c & 1) ? dzo : 0);
                atomicAdd(&hist[cell * 64 + ptl], 1);
            }
        }
    }
    __syncthreads();
    // exclusive scan of 13824 = 256 threads * 54
    int sum = 0;
    for (int j = 0; j < 54; ++j) sum += hist[tid * 54 + j];
    part[tid] = sum;
    __syncthreads();
    if (tid == 0) {
        int run = 0;
        for (int i = 0; i < 256; ++i) { int v = part[i]; part[i] = run; run += v; }
        part[256] = run;
    }
    __syncthreads();
    {
        int run = part[tid];
        for (int j = 0; j < 54; ++j) {
            int i = tid * 54 + j;
            int v = hist[i]; hist[i] = run; run += v;
        }
    }
    __syncthreads();
    // coarse starts at (cell, wavegroup-of-16-pts) granularity
    for (int i = tid; i < 864; i += 256)
        starts[sg * 865 + i] = hist[(i >> 2) * 64 + (i & 3) * 16];
    if (tid == 0) starts[sg * 865 + 864] = part[256];
    __syncthreads();
    // scatter (fine cursors in hist)
    uint2* cb = contribs + (size_t)sg * 16384;
    for (int r = tid; r < nrec; r += 256) {
        uint4 g = gb[r];
        if (g.w & 2048u) {
            int ptl = r >> 5;
            float fx = __uint_as_float(g.x);
            float fy = __uint_as_float(g.y);
            float fz = __uint_as_float(g.z);
            int c000 = g.w & 255u;
            int dxo = (g.w & 256u)  ? 36 : 0;
            int dyo = (g.w & 512u)  ? 6  : 0;
            int dzo = (g.w & 1024u) ? 1  : 0;
            int nid = (g.w >> 12) & 16383u;
            unsigned pay = (unsigned)nid | ((unsigned)ptl << 14);
            #pragma unroll
            for (int c = 0; c < 8; ++c) {
                float wgt = ((c & 4) ? fx : 1.f - fx)
                          * ((c & 2) ? fy : 1.f - fy)
                          * ((c & 1) ? fz : 1.f - fz);
                int cell = c000 + ((c & 4) ? dxo : 0) + ((c & 2) ? dyo : 0)
                                + ((c & 1) ? dzo : 0);
                int p = atomicAdd(&hist[cell * 64 + ptl], 1);
                cb[p] = make_uint2(__float_as_uint(wgt), pay);
            }
        }
    }
}

// ---------------------------------------------------------------------------
// Kernel 3: conv as tiled GEMM. Block = MT pts x COUT. Per cell-chunk:
// wave-local A-tile zero + register-accumulated scatter (sorted by pt -> one
// LDS write per (cell,pt) group, no RMW), double-buffered W tile (register
// prefetch), then 4pt x 4co per-thread register-tile FMA GEMM from LDS.
// K-split across blockIdx.y into partial buffers (combined later).
// ---------------------------------------------------------------------------
template<int CIN, int COUT, int CPC, int MT, int KSPLIT>
__global__ __launch_bounds__(256, 2) void conv_kernel(
    const float* __restrict__ feats, const float* __restrict__ W,
    const uint2* __restrict__ contribs, const int* __restrict__ starts,
    float* __restrict__ partial) {
    constexpr int KC   = CPC * CIN;       // K per chunk (64/64/32)
    constexpr int ASTR = KC + 4;          // +4 pad: 2-way LDS aliasing (free)
    constexpr int CG   = COUT / 4;        // co groups (16 or 8)
    constexpr int NSG  = MT / 64;         // sort groups per block (1 or 2)
    constexpr int NCHUNK = NCELL / CPC;
    constexpr int NWG  = (NSG == 2) ? 2 : 1;
    constexpr int WPT  = (KC * COUT) / 1024;  // W float4s per thread
    constexpr int RPW  = MT / 4;              // A rows owned per wave

    __shared__ alignas(16) float Al[MT * ASTR];
    __shared__ alignas(16) float Wl[2][KC * COUT];
    __shared__ int Sl[NSG][868];

    const int tid  = threadIdx.x;
    const int lane = tid & 63;
    const int wv   = tid >> 6;
    const int cg   = tid % CG;
    const int pg   = tid / CG;
    const int bx   = blockIdx.x;
    const int ks   = blockIdx.y;

    for (int s = 0; s < NSG; ++s) {
        int sg = bx * NSG + s;
        for (int i = tid; i < 865; i += 256)
            Sl[s][i] = (sg < NSGT) ? starts[sg * 865 + i] : 0;
    }
    __syncthreads();

    const int c0 = NCHUNK * ks / KSPLIT;
    const int c1 = NCHUNK * (ks + 1) / KSPLIT;

    const int sgl = (NSG == 2) ? (wv >> 1) : 0;
    const int wg0 = (NSG == 2) ? ((wv & 1) * 2) : wv;
    const uint2* cb = contribs + (size_t)(bx * NSG + sgl) * 16384;

    // stage = zero wave-owned A rows + scatter chunk's contributions
    auto stage = [&](int c) {
        float4 z4; z4.x = z4.y = z4.z = z4.w = 0.f;
        float4* Az = reinterpret_cast<float4*>(Al + wv * RPW * ASTR);
        for (int i = lane; i < RPW * (ASTR / 4); i += 64) Az[i] = z4;
        const int cellbase = c * CPC;
        for (int cl = 0; cl < CPC; ++cl) {
            const int m = cellbase + cl;
            const int key = m * 4 + wg0;
            int s = Sl[sgl][key];
            int e = Sl[sgl][key + NWG];
            if (s >= e) continue;
            const int kb = cl * CIN;
            float vacc = 0.f;
            int prevpt = -1;
            int i = s;
            while (i < e) {
                int n2 = min(64, e - i);
                uint2 rec = make_uint2(0u, 0u);
                if (lane < n2) rec = cb[i + lane];
                for (int t = 0; t < n2; ++t) {
                    float wgt = __shfl(__uint_as_float(rec.x), t);
                    int pay   = __shfl((int)rec.y, t);
                    int ptl = (pay >> 14) & 63;
                    if (ptl != prevpt) {
                        if (prevpt >= 0 && lane < CIN)
                            Al[(sgl * 64 + prevpt) * ASTR + kb + lane] = vacc;
                        vacc = 0.f;
                        prevpt = ptl;
                    }
                    int nid = pay & 16383;
                    float f = (lane < CIN) ? feats[(size_t)nid * CIN + lane] : 0.f;
                    vacc = fmaf(wgt, f, vacc);
                }
                i += n2;
            }
            if (prevpt >= 0 && lane < CIN)
                Al[(sgl * 64 + prevpt) * ASTR + kb + lane] = vacc;
        }
    };

    // prologue: stage W chunk c0 directly + A chunk c0
    {
        const float4* Wg = reinterpret_cast<const float4*>(W + (size_t)c0 * KC * COUT);
        float4* Wd = reinterpret_cast<float4*>(Wl[0]);
        for (int i = tid; i < KC * COUT / 4; i += 256) Wd[i] = Wg[i];
    }
    stage(c0);
    __syncthreads();

    float4 acc[4];
    #pragma unroll
    for (int p = 0; p < 4; ++p) { acc[p].x = acc[p].y = acc[p].z = acc[p].w = 0.f; }

    for (int c = c0; c < c1; ++c) {
        const int b = (c - c0) & 1;
        float4 wpre[WPT];
        if (c + 1 < c1) {
            const float4* Wg = reinterpret_cast<const float4*>(W + (size_t)(c + 1) * KC * COUT);
            #pragma unroll
            for (int j = 0; j < WPT; ++j) wpre[j] = Wg[tid + j * 256];
        }
        // GEMM on chunk c
        const float* Wb = Wl[b];
        #pragma unroll 2
        for (int g = 0; g < KC / 4; ++g) {
            float4 wf[4];
            #pragma unroll
            for (int j = 0; j < 4; ++j)
                wf[j] = *reinterpret_cast<const float4*>(Wb + (g * 4 + j) * COUT + cg * 4);
            float4 af[4];
            #pragma unroll
            for (int p = 0; p < 4; ++p)
                af[p] = *reinterpret_cast<const float4*>(Al + (pg * 4 + p) * ASTR + g * 4);
            #pragma unroll
            for (int p = 0; p < 4; ++p) {
                const float* afp = reinterpret_cast<const float*>(&af[p]);
                #pragma unroll
                for (int j = 0; j < 4; ++j) {
                    float a = afp[j];
                    acc[p].x = fmaf(a, wf[j].x, acc[p].x);
                    acc[p].y = fmaf(a, wf[j].y, acc[p].y);
                    acc[p].z = fmaf(a, wf[j].z, acc[p].z);
                    acc[p].w = fmaf(a, wf[j].w, acc[p].w);
                }
            }
        }
        __syncthreads();
        if (c + 1 < c1) {
            float4* Wd = reinterpret_cast<float4*>(Wl[b ^ 1]);
            #pragma unroll
            for (int j = 0; j < WPT; ++j) Wd[tid + j * 256] = wpre[j];
            stage(c + 1);
        }
        __syncthreads();
    }

    #pragma unroll
    for (int p = 0; p < 4; ++p) {
        int n = bx * MT + pg * 4 + p;
        if (n < NPTS)
            *reinterpret_cast<float4*>(partial + ((size_t)ks * NPTS + n) * COUT + cg * 4) = acc[p];
    }
}

// ---------------------------------------------------------------------------
// Kernel 4: combine K-split partials, normalize by neighbor count, bias, relu.
// ---------------------------------------------------------------------------
template<int COUT, int KSPLIT>
__global__ __launch_bounds__(256) void combine_kernel(
    const float* __restrict__ partial, const float* __restrict__ cnt,
    const float* __restrict__ bias, float* __restrict__ out) {
    int idx = blockIdx.x * 256 + threadIdx.x;
    if (idx >= NPTS * COUT) return;
    int n = idx / COUT, co = idx % COUT;
    float s = 0.f;
    #pragma unroll
    for (int k2 = 0; k2 < KSPLIT; ++k2)
        s += partial[((size_t)k2 * NPTS + n) * COUT + co];
    float c = cnt[n];
    if (c > 0.f) s /= fmaxf(c, 1.f);
    out[idx] = fmaxf(s + bias[co], 0.f);
}

// ---------------------------------------------------------------------------
// Kernel 5: fused FC chain. One wave per point, __shfl broadcasts.
// ---------------------------------------------------------------------------
__global__ __launch_bounds__(64) void fc_kernel(
    const float* __restrict__ x,
    const float* __restrict__ W1, const float* __restrict__ b1,
    const float* __restrict__ W2, const float* __restrict__ b2,
    const float* __restrict__ W3, const float* __restrict__ b3,
    const float* __restrict__ W4, const float* __restrict__ b4,
    float* __restrict__ out) {
    int n = blockIdx.x;
    int lane = threadIdx.x;
    float xv = (lane < 32) ? x[(size_t)n * 32 + lane] : 0.0f;

    float t = b1[lane];
    for (int ci = 0; ci < 32; ++ci)
        t = fmaf(__shfl(xv, ci), W1[ci * 64 + lane], t);
    float h1 = fmaxf(t, 0.0f);

    t = b2[lane];
    for (int ci = 0; ci < 64; ++ci)
        t = fmaf(__shfl(h1, ci), W2[ci * 64 + lane], t);
    float h2 = fmaxf(t, 0.0f);

    int l32 = lane & 31;
    t = b3[l32];
    for (int ci = 0; ci < 64; ++ci)
        t = fmaf(__shfl(h2, ci), W3[ci * 32 + l32], t);
    float h3 = fmaxf(t, 0.0f);

    int ch = (lane < 3) ? lane : 0;
    float o = b4[ch];
    for (int ci = 0; ci < 32; ++ci)
        o = fmaf(__shfl(h3, ci), W4[ci * 3 + ch], o);
    if (lane < 3) out[(size_t)n * 3 + lane] = o;
}

// ---------------------------------------------------------------------------
// launch
// ---------------------------------------------------------------------------
extern "C" void kernel_launch(void* const* d_in, const int* in_sizes, int n_in,
                              void* d_out, int out_size, void* d_ws, size_t ws_size,
                              hipStream_t stream) {
    const float* feats = (const float*)d_in[0];
    const float* pos   = (const float*)d_in[1];
    const int*   nidx  = (const int*)d_in[2];
    // d_in[3] (neighbor_mask) unused: mask recomputed exactly.
    const float* W1 = (const float*)d_in[4];
    const float* b1 = (const float*)d_in[5];
    const float* W2 = (const float*)d_in[6];
    const float* b2 = (const float*)d_in[7];
    const float* W3 = (const float*)d_in[8];
    const float* b3 = (const float*)d_in[9];
    const float* Wfc1 = (const float*)d_in[10];
    const float* bfc1 = (const float*)d_in[11];
    const float* Wfc2 = (const float*)d_in[12];
    const float* bfc2 = (const float*)d_in[13];
    const float* Wfc3 = (const float*)d_in[14];
    const float* bfc3 = (const float*)d_in[15];
    const float* Wout = (const float*)d_in[16];
    const float* bout = (const float*)d_in[17];

    char* ws = (char*)d_ws;
    uint4* geo     = (uint4*)(ws);                    //  5,120,000 B
    uint2* contrib = (uint2*)(ws + 5120000);          // 20,578,304 B
    float* partial = (float*)(ws + 25698304);         //  5,120,000 B
    float* x1      = (float*)(ws + 30818304);         //  2,560,000 B
    float* x2      = (float*)(ws + 33378304);         //  2,560,000 B
    float* x3      = (float*)(ws + 35938304);         //  1,280,000 B
    float* cnt     = (float*)(ws + 37218304);         //     40,000 B
    int*   starts  = (int*)  (ws + 37258304);         //    543,220 B

    hipMemsetAsync(cnt, 0, NPTS * sizeof(float), stream);
    geom_kernel<<<(NPTS * KNB) / 256, 256, 0, stream>>>(pos, nidx, geo, cnt);
    sort_kernel<<<NSGT, 256, 0, stream>>>(geo, contrib, starts);

    conv_kernel<4, 64, 8, 64, 2><<<dim3(157, 2), 256, 0, stream>>>(
        feats, W1, contrib, starts, partial);
    combine_kernel<64, 2><<<(NPTS * 64 + 255) / 256, 256, 0, stream>>>(
        partial, cnt, b1, x1);

    conv_kernel<64, 64, 1, 64, 2><<<dim3(157, 2), 256, 0, stream>>>(
        x1, W2, contrib, starts, partial);
    combine_kernel<64, 2><<<(NPTS * 64 + 255) / 256, 256, 0, stream>>>(
        partial, cnt, b2, x2);

    conv_kernel<64, 32, 1, 128, 4><<<dim3(79, 4), 256, 0, stream>>>(
        x2, W3, contrib, starts, partial);
    combine_kernel<32, 4><<<(NPTS * 32 + 255) / 256, 256, 0, stream>>>(
        partial, cnt, b3, x3);

    fc_kernel<<<NPTS, 64, 0, stream>>>(x3, Wfc1, bfc1, Wfc2, bfc2,
                                       Wfc3, bfc3, Wout, bout, (float*)d_out);
}